// Round 1
// baseline (285.140 us; speedup 1.0000x reference)
//
#include <hip/hip_runtime.h>
#include <hip/hip_bf16.h>

// ---------- helpers ----------
typedef __bf16 bf16x8 __attribute__((ext_vector_type(8)));
typedef float f32x4 __attribute__((ext_vector_type(4)));
typedef unsigned short u16x8 __attribute__((ext_vector_type(8)));

__device__ __forceinline__ unsigned short f2bf(float f) {
  unsigned u = __float_as_uint(f);
  u += 0x7FFF + ((u >> 16) & 1);          // RNE
  return (unsigned short)(u >> 16);
}
__device__ __forceinline__ float bf2f(unsigned short h) {
  return __uint_as_float((unsigned)h << 16);
}

__device__ __forceinline__ void gload_lds16(const void* g, void* l) {
  __builtin_amdgcn_global_load_lds(
      (const __attribute__((address_space(1))) void*)g,
      (__attribute__((address_space(3))) void*)l, 16, 0, 0);
}

// ---------- 1) row softmax of 4 P matrices -> bf16 ----------
__global__ __launch_bounds__(256)
void softmax4_kernel(const float* __restrict__ P0, const float* __restrict__ P1,
                     const float* __restrict__ P2, const float* __restrict__ P3,
                     unsigned short* __restrict__ S)
{
  const int bid = blockIdx.x;
  const int mat = bid >> 10, row = bid & 1023;
  const float* P = (mat == 0 ? P0 : mat == 1 ? P1 : mat == 2 ? P2 : P3) + (size_t)row * 1024;
  unsigned short* out = S + ((size_t)mat << 20) + (size_t)row * 1024;
  const int t = threadIdx.x, w = t >> 6, l = t & 63;
  float4 v = ((const float4*)P)[t];
  float mx = fmaxf(fmaxf(v.x, v.y), fmaxf(v.z, v.w));
  #pragma unroll
  for (int off = 32; off > 0; off >>= 1) mx = fmaxf(mx, __shfl_xor(mx, off));
  __shared__ float redA[4], redB[4];
  if (l == 0) redA[w] = mx;
  __syncthreads();
  mx = fmaxf(fmaxf(redA[0], redA[1]), fmaxf(redA[2], redA[3]));
  float e0 = __expf(v.x - mx), e1 = __expf(v.y - mx);
  float e2 = __expf(v.z - mx), e3 = __expf(v.w - mx);
  float s = e0 + e1 + e2 + e3;
  #pragma unroll
  for (int off = 32; off > 0; off >>= 1) s += __shfl_xor(s, off);
  if (l == 0) redB[w] = s;
  __syncthreads();
  s = redB[0] + redB[1] + redB[2] + redB[3];
  float inv = 1.0f / s;
  ushort4 o;
  o.x = f2bf(e0 * inv); o.y = f2bf(e1 * inv);
  o.z = f2bf(e2 * inv); o.w = f2bf(e3 * inv);
  ((ushort4*)out)[t] = o;
}

// ---------- 2) out^T = (blockdiag(K)^T @ in)^T,  K:[32][32][32] fp32, in/out bf16 ----------
// out[n*32+o, c] = sum_i K[n][i][o] * in[n*32+i, c];  we store outT[c, n*32+o]
__global__ __launch_bounds__(256)
void blockdiagT_kernel(const float* __restrict__ Kb, const unsigned short* __restrict__ in,
                       unsigned short* __restrict__ outT)
{
  const int n = blockIdx.x;                      // 0..31
  const int c = blockIdx.y * 256 + threadIdx.x;  // 0..1023
  __shared__ float Ks[32][33];                   // Ks[i][o]
  for (int t = threadIdx.x; t < 1024; t += 256)
    Ks[t >> 5][t & 31] = Kb[n * 1024 + t];
  __syncthreads();
  float ri[32];
  #pragma unroll
  for (int i = 0; i < 32; ++i)
    ri[i] = bf2f(in[(size_t)(n * 32 + i) * 1024 + c]);
  unsigned short ov[32];
  #pragma unroll
  for (int o = 0; o < 32; ++o) {
    float acc = 0.f;
    #pragma unroll
    for (int i = 0; i < 32; ++i) acc = fmaf(Ks[i][o], ri[i], acc);
    ov[o] = f2bf(acc);
  }
  u16x8* dst = (u16x8*)(outT + (size_t)c * 1024 + n * 32);
  const u16x8* src = (const u16x8*)ov;
  #pragma unroll
  for (int q = 0; q < 4; ++q) dst[q] = src[q];
}

// ---------- 3) GEMM: C[M,N] = A[M,K] @ B^T  (B stored [N,K] row-major, bf16) ----------
// A_FP32: A is fp32, converted to bf16 during LDS staging. OUT_BIAS: fp32 out + bias.
template<bool A_FP32, bool OUT_BIAS>
__global__ __launch_bounds__(256)
void gemm_bt_kernel(const void* __restrict__ Av, const unsigned short* __restrict__ B,
                    void* __restrict__ Cv, const float* __restrict__ bias,
                    int M, int N, int K)
{
  __shared__ unsigned short Asm[128 * 64];
  __shared__ unsigned short Bsm[128 * 64];
  const int tid = threadIdx.x;
  const int w = tid >> 6, l = tid & 63;
  const int n0 = blockIdx.x * 128, m0 = blockIdx.y * 128;
  const int wr = (w >> 1) * 64, wc = (w & 1) * 64;   // wave 2x2 grid, 64x64 each
  const int lr = l & 15, kg = (l >> 4) << 3;

  f32x4 acc[4][4] = {};

  const int KT = K >> 6;
  for (int kt = 0; kt < KT; ++kt) {
    const int k0 = kt << 6;
    if (kt) __syncthreads();
    // stage B tile [128 n][64 k] via async global->LDS (16B/lane)
    #pragma unroll
    for (int it = 0; it < 4; ++it) {
      int li = it * 256 + tid;
      int row = li >> 3, c8 = (li & 7) << 3;
      const unsigned short* g = B + (size_t)(n0 + row) * K + (k0 + c8);
      gload_lds16(g, (char*)Bsm + it * 4096 + w * 1024);
    }
    // stage A tile [128 m][64 k]
    if (A_FP32) {
      const float* Af = (const float*)Av;
      #pragma unroll
      for (int p = 0; p < 4; ++p) {
        int row = (tid >> 3) + p * 32;
        int c8 = (tid & 7) << 3;
        const float* g = Af + (size_t)(m0 + row) * K + (k0 + c8);
        float4 v0 = ((const float4*)g)[0];
        float4 v1 = ((const float4*)g)[1];
        u16x8 uv;
        uv[0] = f2bf(v0.x); uv[1] = f2bf(v0.y); uv[2] = f2bf(v0.z); uv[3] = f2bf(v0.w);
        uv[4] = f2bf(v1.x); uv[5] = f2bf(v1.y); uv[6] = f2bf(v1.z); uv[7] = f2bf(v1.w);
        *(u16x8*)&Asm[row * 64 + c8] = uv;
      }
    } else {
      const unsigned short* Ab = (const unsigned short*)Av;
      #pragma unroll
      for (int it = 0; it < 4; ++it) {
        int li = it * 256 + tid;
        int row = li >> 3, c8 = (li & 7) << 3;
        const unsigned short* g = Ab + (size_t)(m0 + row) * K + (k0 + c8);
        gload_lds16(g, (char*)Asm + it * 4096 + w * 1024);
      }
    }
    __syncthreads();
    // compute: 2 k-steps of 32, 4x4 fragments of 16x16x32
    #pragma unroll
    for (int ks = 0; ks < 2; ++ks) {
      const int kb = ks * 32 + kg;
      bf16x8 af[4], bfr[4];
      #pragma unroll
      for (int i = 0; i < 4; ++i)
        af[i] = *(const bf16x8*)&Asm[(wr + i * 16 + lr) * 64 + kb];
      #pragma unroll
      for (int j = 0; j < 4; ++j)
        bfr[j] = *(const bf16x8*)&Bsm[(wc + j * 16 + lr) * 64 + kb];
      #pragma unroll
      for (int i = 0; i < 4; ++i)
        #pragma unroll
        for (int j = 0; j < 4; ++j)
          acc[i][j] = __builtin_amdgcn_mfma_f32_16x16x32_bf16(af[i], bfr[j], acc[i][j], 0, 0, 0);
    }
  }

  // epilogue: C/D layout col = lane&15, row = (lane>>4)*4 + reg  [verified m89/m91]
  const int cr = (l >> 4) << 2;
  const int cc = l & 15;
  if (OUT_BIAS) {
    float* C = (float*)Cv;
    #pragma unroll
    for (int j = 0; j < 4; ++j) {
      int col = n0 + wc + j * 16 + cc;
      float bv = bias[col];
      #pragma unroll
      for (int i = 0; i < 4; ++i) {
        int rbase = m0 + wr + i * 16 + cr;
        #pragma unroll
        for (int r = 0; r < 4; ++r)
          C[(size_t)(rbase + r) * N + col] = acc[i][j][r] + bv;
      }
    }
  } else {
    unsigned short* C = (unsigned short*)Cv;
    #pragma unroll
    for (int j = 0; j < 4; ++j) {
      int col = n0 + wc + j * 16 + cc;
      #pragma unroll
      for (int i = 0; i < 4; ++i) {
        int rbase = m0 + wr + i * 16 + cr;
        #pragma unroll
        for (int r = 0; r < 4; ++r)
          C[(size_t)(rbase + r) * N + col] = f2bf(acc[i][j][r]);
      }
    }
  }
}

// ---------- launch ----------
extern "C" void kernel_launch(void* const* d_in, const int* in_sizes, int n_in,
                              void* d_out, int out_size, void* d_ws, size_t ws_size,
                              hipStream_t stream) {
  (void)in_sizes; (void)n_in; (void)out_size; (void)ws_size;
  const float* x    = (const float*)d_in[0];
  const float* P0   = (const float*)d_in[1];
  const float* P1   = (const float*)d_in[2];
  const float* P2   = (const float*)d_in[3];
  const float* P3   = (const float*)d_in[4];
  const float* K0   = (const float*)d_in[5];
  const float* K1   = (const float*)d_in[6];
  const float* K2   = (const float*)d_in[7];
  const float* bias = (const float*)d_in[8];

  // ws layout (bf16 elements): S0..S3 (4 x 1M), T0 (1M), T1 (1M) = 12 MiB total
  unsigned short* S  = (unsigned short*)d_ws;
  unsigned short* T0 = S + (size_t)4 * (1u << 20);
  unsigned short* T1 = T0 + (1u << 20);

  // 1) softmax of all 4 P matrices -> bf16
  softmax4_kernel<<<4096, 256, 0, stream>>>(P0, P1, P2, P3, S);

  const unsigned short* S0 = S;
  const unsigned short* S1 = S + (1u << 20);
  const unsigned short* S2 = S + (2u << 20);
  const unsigned short* S3 = S + (3u << 20);

  // 2) compose M = S3 @ Bd2^T @ S2 @ Bd1^T @ S1 @ Bd0^T @ S0  (right to left)
  dim3 bdg(32, 4), gg(8, 8);
  blockdiagT_kernel<<<bdg, 256, 0, stream>>>(K0, S0, T0);                       // T0 = (Bd0^T S0)^T
  gemm_bt_kernel<false, false><<<gg, 256, 0, stream>>>((const void*)S1, T0,
                                                       (void*)T1, nullptr, 1024, 1024, 1024); // T1 = S1 Bd0^T S0
  blockdiagT_kernel<<<bdg, 256, 0, stream>>>(K1, T1, T0);                       // T0 = (Bd1^T T1)^T
  gemm_bt_kernel<false, false><<<gg, 256, 0, stream>>>((const void*)S2, T0,
                                                       (void*)T1, nullptr, 1024, 1024, 1024);
  blockdiagT_kernel<<<bdg, 256, 0, stream>>>(K2, T1, T0);                       // T0 = (Bd2^T T1)^T
  gemm_bt_kernel<false, false><<<gg, 256, 0, stream>>>((const void*)S3, T0,
                                                       (void*)T1, nullptr, 1024, 1024, 1024); // T1 = M [u][d]

  // 3) out[b,u] = sum_d x[b,d] * M[u,d] + bias[u]
  dim3 gf(8, 256);  // n-tiles fast -> 8 consecutive blocks share the same A (x) tile
  gemm_bt_kernel<true, true><<<gf, 256, 0, stream>>>((const void*)x, T1,
                                                     d_out, bias, 32768, 1024, 1024);
}

// Round 2
// 214.408 us; speedup vs baseline: 1.3299x; 1.3299x over previous
//
#include <hip/hip_runtime.h>
#include <hip/hip_bf16.h>

// ---------- helpers ----------
typedef __bf16 bf16x8 __attribute__((ext_vector_type(8)));
typedef float f32x4 __attribute__((ext_vector_type(4)));
typedef unsigned short u16x8 __attribute__((ext_vector_type(8)));

__device__ __forceinline__ unsigned short f2bf(float f) {
  unsigned u = __float_as_uint(f);
  u += 0x7FFF + ((u >> 16) & 1);          // RNE
  return (unsigned short)(u >> 16);
}
__device__ __forceinline__ float bf2f(unsigned short h) {
  return __uint_as_float((unsigned)h << 16);
}

__device__ __forceinline__ void gload_lds16(const void* g, void* l) {
  __builtin_amdgcn_global_load_lds(
      (const __attribute__((address_space(1))) void*)g,
      (__attribute__((address_space(3))) void*)l, 16, 0, 0);
}

// ---------- 1) row softmax of 4 P matrices -> bf16 ----------
__global__ __launch_bounds__(256)
void softmax4_kernel(const float* __restrict__ P0, const float* __restrict__ P1,
                     const float* __restrict__ P2, const float* __restrict__ P3,
                     unsigned short* __restrict__ S)
{
  const int bid = blockIdx.x;
  const int mat = bid >> 10, row = bid & 1023;
  const float* P = (mat == 0 ? P0 : mat == 1 ? P1 : mat == 2 ? P2 : P3) + (size_t)row * 1024;
  unsigned short* out = S + ((size_t)mat << 20) + (size_t)row * 1024;
  const int t = threadIdx.x, w = t >> 6, l = t & 63;
  float4 v = ((const float4*)P)[t];
  float mx = fmaxf(fmaxf(v.x, v.y), fmaxf(v.z, v.w));
  #pragma unroll
  for (int off = 32; off > 0; off >>= 1) mx = fmaxf(mx, __shfl_xor(mx, off));
  __shared__ float redA[4], redB[4];
  if (l == 0) redA[w] = mx;
  __syncthreads();
  mx = fmaxf(fmaxf(redA[0], redA[1]), fmaxf(redA[2], redA[3]));
  float e0 = __expf(v.x - mx), e1 = __expf(v.y - mx);
  float e2 = __expf(v.z - mx), e3 = __expf(v.w - mx);
  float s = e0 + e1 + e2 + e3;
  #pragma unroll
  for (int off = 32; off > 0; off >>= 1) s += __shfl_xor(s, off);
  if (l == 0) redB[w] = s;
  __syncthreads();
  s = redB[0] + redB[1] + redB[2] + redB[3];
  float inv = 1.0f / s;
  ushort4 o;
  o.x = f2bf(e0 * inv); o.y = f2bf(e1 * inv);
  o.z = f2bf(e2 * inv); o.w = f2bf(e3 * inv);
  ((ushort4*)out)[t] = o;
}

// ---------- 1b) x fp32 -> bf16 one-shot convert ----------
__global__ __launch_bounds__(256)
void convert_x_kernel(const float* __restrict__ x, unsigned short* __restrict__ xb, int n8)
{
  int i = blockIdx.x * 256 + threadIdx.x;
  const int stride = gridDim.x * 256;
  for (; i < n8; i += stride) {
    float4 v0 = ((const float4*)x)[2 * i];
    float4 v1 = ((const float4*)x)[2 * i + 1];
    u16x8 uv;
    uv[0] = f2bf(v0.x); uv[1] = f2bf(v0.y); uv[2] = f2bf(v0.z); uv[3] = f2bf(v0.w);
    uv[4] = f2bf(v1.x); uv[5] = f2bf(v1.y); uv[6] = f2bf(v1.z); uv[7] = f2bf(v1.w);
    ((u16x8*)xb)[i] = uv;
  }
}

// ---------- 2) out^T = (blockdiag(K)^T @ in)^T,  K:[32][32][32] fp32, in/out bf16 ----------
__global__ __launch_bounds__(256)
void blockdiagT_kernel(const float* __restrict__ Kb, const unsigned short* __restrict__ in,
                       unsigned short* __restrict__ outT)
{
  const int n = blockIdx.x;                      // 0..31
  const int c = blockIdx.y * 256 + threadIdx.x;  // 0..1023
  __shared__ float Ks[32][33];                   // Ks[i][o]
  for (int t = threadIdx.x; t < 1024; t += 256)
    Ks[t >> 5][t & 31] = Kb[n * 1024 + t];
  __syncthreads();
  float ri[32];
  #pragma unroll
  for (int i = 0; i < 32; ++i)
    ri[i] = bf2f(in[(size_t)(n * 32 + i) * 1024 + c]);
  unsigned short ov[32];
  #pragma unroll
  for (int o = 0; o < 32; ++o) {
    float acc = 0.f;
    #pragma unroll
    for (int i = 0; i < 32; ++i) acc = fmaf(Ks[i][o], ri[i], acc);
    ov[o] = f2bf(acc);
  }
  u16x8* dst = (u16x8*)(outT + (size_t)c * 1024 + n * 32);
  const u16x8* src = (const u16x8*)ov;
  #pragma unroll
  for (int q = 0; q < 4; ++q) dst[q] = src[q];
}

// ---------- 3) GEMM: C[M,N] = A[M,K] @ B^T  (B stored [N,K] row-major, bf16) ----------
// TILE in {64,128}. A_FP32: convert A fp32->bf16 in staging (fallback path only).
// 1D grid, bijective XCD swizzle (requires gridDim.x % 8 == 0).
template<int TILE, bool A_FP32, bool OUT_BIAS>
__global__ __launch_bounds__(256)
void gemm_bt_kernel(const void* __restrict__ Av, const unsigned short* __restrict__ B,
                    void* __restrict__ Cv, const float* __restrict__ bias,
                    int M, int N, int K)
{
  constexpr int FR  = TILE / 32;   // 16x16 fragments per wave dim
  constexpr int SIT = TILE / 32;   // staging passes per tile (256 lanes x 16B each)
  __shared__ unsigned short Asm[TILE * 64];
  __shared__ unsigned short Bsm[TILE * 64];
  const int tid = threadIdx.x;
  const int w = tid >> 6, l = tid & 63;

  // XCD-aware swizzle: XCD x gets a contiguous chunk of tile space
  const int nwg = gridDim.x;
  const int bid = blockIdx.x;
  const int cpx = nwg >> 3;
  const int swz = (bid & 7) * cpx + (bid >> 3);
  const int ntn = N / TILE;
  const int n0 = (swz % ntn) * TILE;
  const int m0 = (swz / ntn) * TILE;

  const int wr = (w >> 1) * (TILE / 2), wc = (w & 1) * (TILE / 2);
  const int lr = l & 15, kg = (l >> 4) << 3;

  f32x4 acc[FR][FR] = {};

  const int KT = K >> 6;
  for (int kt = 0; kt < KT; ++kt) {
    const int k0 = kt << 6;
    if (kt) __syncthreads();
    // stage B tile [TILE n][64 k]
    #pragma unroll
    for (int it = 0; it < SIT; ++it) {
      int li = it * 256 + tid;
      int row = li >> 3, c8 = (li & 7) << 3;
      const unsigned short* g = B + (size_t)(n0 + row) * K + (k0 + c8);
      gload_lds16(g, (char*)Bsm + it * 4096 + w * 1024);
    }
    // stage A tile [TILE m][64 k]
    if (A_FP32) {
      const float* Af = (const float*)Av;
      #pragma unroll
      for (int p = 0; p < SIT; ++p) {
        int row = (tid >> 3) + p * 32;
        int c8 = (tid & 7) << 3;
        const float* g = Af + (size_t)(m0 + row) * K + (k0 + c8);
        float4 v0 = ((const float4*)g)[0];
        float4 v1 = ((const float4*)g)[1];
        u16x8 uv;
        uv[0] = f2bf(v0.x); uv[1] = f2bf(v0.y); uv[2] = f2bf(v0.z); uv[3] = f2bf(v0.w);
        uv[4] = f2bf(v1.x); uv[5] = f2bf(v1.y); uv[6] = f2bf(v1.z); uv[7] = f2bf(v1.w);
        *(u16x8*)&Asm[row * 64 + c8] = uv;
      }
    } else {
      const unsigned short* Ab = (const unsigned short*)Av;
      #pragma unroll
      for (int it = 0; it < SIT; ++it) {
        int li = it * 256 + tid;
        int row = li >> 3, c8 = (li & 7) << 3;
        const unsigned short* g = Ab + (size_t)(m0 + row) * K + (k0 + c8);
        gload_lds16(g, (char*)Asm + it * 4096 + w * 1024);
      }
    }
    __syncthreads();
    #pragma unroll
    for (int ks = 0; ks < 2; ++ks) {
      const int kb = ks * 32 + kg;
      bf16x8 af[FR], bfr[FR];
      #pragma unroll
      for (int i = 0; i < FR; ++i)
        af[i] = *(const bf16x8*)&Asm[(wr + i * 16 + lr) * 64 + kb];
      #pragma unroll
      for (int j = 0; j < FR; ++j)
        bfr[j] = *(const bf16x8*)&Bsm[(wc + j * 16 + lr) * 64 + kb];
      #pragma unroll
      for (int i = 0; i < FR; ++i)
        #pragma unroll
        for (int j = 0; j < FR; ++j)
          acc[i][j] = __builtin_amdgcn_mfma_f32_16x16x32_bf16(af[i], bfr[j], acc[i][j], 0, 0, 0);
    }
  }

  // epilogue: C/D layout col = lane&15, row = (lane>>4)*4 + reg  [verified m89/m91]
  const int cr = (l >> 4) << 2;
  const int cc = l & 15;
  if (OUT_BIAS) {
    float* C = (float*)Cv;
    #pragma unroll
    for (int j = 0; j < FR; ++j) {
      int col = n0 + wc + j * 16 + cc;
      float bv = bias[col];
      #pragma unroll
      for (int i = 0; i < FR; ++i) {
        int rbase = m0 + wr + i * 16 + cr;
        #pragma unroll
        for (int r = 0; r < 4; ++r)
          C[(size_t)(rbase + r) * N + col] = acc[i][j][r] + bv;
      }
    }
  } else {
    unsigned short* C = (unsigned short*)Cv;
    #pragma unroll
    for (int j = 0; j < FR; ++j) {
      int col = n0 + wc + j * 16 + cc;
      #pragma unroll
      for (int i = 0; i < FR; ++i) {
        int rbase = m0 + wr + i * 16 + cr;
        #pragma unroll
        for (int r = 0; r < 4; ++r)
          C[(size_t)(rbase + r) * N + col] = f2bf(acc[i][j][r]);
      }
    }
  }
}

// ---------- launch ----------
extern "C" void kernel_launch(void* const* d_in, const int* in_sizes, int n_in,
                              void* d_out, int out_size, void* d_ws, size_t ws_size,
                              hipStream_t stream) {
  (void)in_sizes; (void)n_in; (void)out_size;
  const float* x    = (const float*)d_in[0];
  const float* P0   = (const float*)d_in[1];
  const float* P1   = (const float*)d_in[2];
  const float* P2   = (const float*)d_in[3];
  const float* P3   = (const float*)d_in[4];
  const float* K0   = (const float*)d_in[5];
  const float* K1   = (const float*)d_in[6];
  const float* K2   = (const float*)d_in[7];
  const float* bias = (const float*)d_in[8];

  // ws layout (bf16 elems): S0..S3 (4 x 1M) | T0 (1M) | T1 (1M) | Xb (32M)
  unsigned short* S  = (unsigned short*)d_ws;
  unsigned short* T0 = S + (size_t)4 * (1u << 20);
  unsigned short* T1 = T0 + (1u << 20);
  unsigned short* Xb = T1 + (1u << 20);
  const size_t need = ((size_t)6 * (1u << 20) + (size_t)32768 * 1024) * 2;
  const bool have_xb = ws_size >= need;

  // 1) softmax of all 4 P matrices -> bf16
  softmax4_kernel<<<4096, 256, 0, stream>>>(P0, P1, P2, P3, S);
  // 1b) x -> bf16
  if (have_xb)
    convert_x_kernel<<<2048, 256, 0, stream>>>(x, Xb, (32768 * 1024) / 8);

  const unsigned short* S0 = S;
  const unsigned short* S1 = S + (1u << 20);
  const unsigned short* S2 = S + (2u << 20);
  const unsigned short* S3 = S + (3u << 20);

  // 2) compose M = S3 @ Bd2^T @ S2 @ Bd1^T @ S1 @ Bd0^T @ S0  (right to left)
  dim3 bdg(32, 4);
  blockdiagT_kernel<<<bdg, 256, 0, stream>>>(K0, S0, T0);
  gemm_bt_kernel<64, false, false><<<256, 256, 0, stream>>>((const void*)S1, T0,
                                                            (void*)T1, nullptr, 1024, 1024, 1024);
  blockdiagT_kernel<<<bdg, 256, 0, stream>>>(K1, T1, T0);
  gemm_bt_kernel<64, false, false><<<256, 256, 0, stream>>>((const void*)S2, T0,
                                                            (void*)T1, nullptr, 1024, 1024, 1024);
  blockdiagT_kernel<<<bdg, 256, 0, stream>>>(K2, T1, T0);
  gemm_bt_kernel<64, false, false><<<256, 256, 0, stream>>>((const void*)S3, T0,
                                                            (void*)T1, nullptr, 1024, 1024, 1024); // T1 = M [u][d]

  // 3) out[b,u] = sum_d x[b,d] * M[u,d] + bias[u]
  if (have_xb) {
    gemm_bt_kernel<128, false, true><<<2048, 256, 0, stream>>>((const void*)Xb, T1,
                                                               d_out, bias, 32768, 1024, 1024);
  } else {
    gemm_bt_kernel<128, true, true><<<2048, 256, 0, stream>>>((const void*)x, T1,
                                                              d_out, bias, 32768, 1024, 1024);
  }
}

// Round 3
// 207.656 us; speedup vs baseline: 1.3731x; 1.0325x over previous
//
#include <hip/hip_runtime.h>
#include <hip/hip_bf16.h>

// ---------- helpers ----------
typedef __bf16 bf16x8 __attribute__((ext_vector_type(8)));
typedef float f32x4 __attribute__((ext_vector_type(4)));
typedef unsigned short u16x8 __attribute__((ext_vector_type(8)));

__device__ __forceinline__ unsigned short f2bf(float f) {
  unsigned u = __float_as_uint(f);
  u += 0x7FFF + ((u >> 16) & 1);          // RNE
  return (unsigned short)(u >> 16);
}
__device__ __forceinline__ float bf2f(unsigned short h) {
  return __uint_as_float((unsigned)h << 16);
}

__device__ __forceinline__ void gload_lds16(const void* g, void* l) {
  __builtin_amdgcn_global_load_lds(
      (const __attribute__((address_space(1))) void*)g,
      (__attribute__((address_space(3))) void*)l, 16, 0, 0);
}

#define LBAR() do { asm volatile("s_waitcnt lgkmcnt(0)" ::: "memory"); \
                    __builtin_amdgcn_s_barrier(); } while (0)

// ---------- 1) row softmax of 4 P matrices -> bf16 ----------
__global__ __launch_bounds__(256)
void softmax4_kernel(const float* __restrict__ P0, const float* __restrict__ P1,
                     const float* __restrict__ P2, const float* __restrict__ P3,
                     unsigned short* __restrict__ S)
{
  const int bid = blockIdx.x;
  const int mat = bid >> 10, row = bid & 1023;
  const float* P = (mat == 0 ? P0 : mat == 1 ? P1 : mat == 2 ? P2 : P3) + (size_t)row * 1024;
  unsigned short* out = S + ((size_t)mat << 20) + (size_t)row * 1024;
  const int t = threadIdx.x, w = t >> 6, l = t & 63;
  float4 v = ((const float4*)P)[t];
  float mx = fmaxf(fmaxf(v.x, v.y), fmaxf(v.z, v.w));
  #pragma unroll
  for (int off = 32; off > 0; off >>= 1) mx = fmaxf(mx, __shfl_xor(mx, off));
  __shared__ float redA[4], redB[4];
  if (l == 0) redA[w] = mx;
  __syncthreads();
  mx = fmaxf(fmaxf(redA[0], redA[1]), fmaxf(redA[2], redA[3]));
  float e0 = __expf(v.x - mx), e1 = __expf(v.y - mx);
  float e2 = __expf(v.z - mx), e3 = __expf(v.w - mx);
  float s = e0 + e1 + e2 + e3;
  #pragma unroll
  for (int off = 32; off > 0; off >>= 1) s += __shfl_xor(s, off);
  if (l == 0) redB[w] = s;
  __syncthreads();
  s = redB[0] + redB[1] + redB[2] + redB[3];
  float inv = 1.0f / s;
  ushort4 o;
  o.x = f2bf(e0 * inv); o.y = f2bf(e1 * inv);
  o.z = f2bf(e2 * inv); o.w = f2bf(e3 * inv);
  ((ushort4*)out)[t] = o;
}

// ---------- 1b) x fp32 -> bf16 one-shot convert ----------
__global__ __launch_bounds__(256)
void convert_x_kernel(const float* __restrict__ x, unsigned short* __restrict__ xb, int n8)
{
  int i = blockIdx.x * 256 + threadIdx.x;
  const int stride = gridDim.x * 256;
  for (; i < n8; i += stride) {
    float4 v0 = ((const float4*)x)[2 * i];
    float4 v1 = ((const float4*)x)[2 * i + 1];
    u16x8 uv;
    uv[0] = f2bf(v0.x); uv[1] = f2bf(v0.y); uv[2] = f2bf(v0.z); uv[3] = f2bf(v0.w);
    uv[4] = f2bf(v1.x); uv[5] = f2bf(v1.y); uv[6] = f2bf(v1.z); uv[7] = f2bf(v1.w);
    ((u16x8*)xb)[i] = uv;
  }
}

// ---------- 2) out^T = (blockdiag(K)^T @ in)^T ----------
__global__ __launch_bounds__(256)
void blockdiagT_kernel(const float* __restrict__ Kb, const unsigned short* __restrict__ in,
                       unsigned short* __restrict__ outT)
{
  const int n = blockIdx.x;
  const int c = blockIdx.y * 256 + threadIdx.x;
  __shared__ float Ks[32][33];
  for (int t = threadIdx.x; t < 1024; t += 256)
    Ks[t >> 5][t & 31] = Kb[n * 1024 + t];
  __syncthreads();
  float ri[32];
  #pragma unroll
  for (int i = 0; i < 32; ++i)
    ri[i] = bf2f(in[(size_t)(n * 32 + i) * 1024 + c]);
  unsigned short ov[32];
  #pragma unroll
  for (int o = 0; o < 32; ++o) {
    float acc = 0.f;
    #pragma unroll
    for (int i = 0; i < 32; ++i) acc = fmaf(Ks[i][o], ri[i], acc);
    ov[o] = f2bf(acc);
  }
  u16x8* dst = (u16x8*)(outT + (size_t)c * 1024 + n * 32);
  const u16x8* src = (const u16x8*)ov;
  #pragma unroll
  for (int q = 0; q < 4; ++q) dst[q] = src[q];
}

// ---------- 3a) 2-barrier GEMM (compose chain + fallback): C = A @ B^T ----------
template<int TILE, bool A_FP32, bool OUT_BIAS>
__global__ __launch_bounds__(256)
void gemm_bt_kernel(const void* __restrict__ Av, const unsigned short* __restrict__ B,
                    void* __restrict__ Cv, const float* __restrict__ bias,
                    int M, int N, int K)
{
  constexpr int FR  = TILE / 32;
  constexpr int SIT = TILE / 32;
  __shared__ unsigned short Asm[TILE * 64];
  __shared__ unsigned short Bsm[TILE * 64];
  const int tid = threadIdx.x;
  const int w = tid >> 6, l = tid & 63;
  const int nwg = gridDim.x;
  const int bid = blockIdx.x;
  const int cpx = nwg >> 3;
  const int swz = (bid & 7) * cpx + (bid >> 3);
  const int ntn = N / TILE;
  const int n0 = (swz % ntn) * TILE;
  const int m0 = (swz / ntn) * TILE;
  const int wr = (w >> 1) * (TILE / 2), wc = (w & 1) * (TILE / 2);
  const int lr = l & 15, kg = (l >> 4) << 3;

  f32x4 acc[FR][FR] = {};
  const int KT = K >> 6;
  for (int kt = 0; kt < KT; ++kt) {
    const int k0 = kt << 6;
    if (kt) __syncthreads();
    #pragma unroll
    for (int it = 0; it < SIT; ++it) {
      int li = it * 256 + tid;
      int row = li >> 3, c8 = (li & 7) << 3;
      const unsigned short* g = B + (size_t)(n0 + row) * K + (k0 + c8);
      gload_lds16(g, (char*)Bsm + it * 4096 + w * 1024);
    }
    if (A_FP32) {
      const float* Af = (const float*)Av;
      #pragma unroll
      for (int p = 0; p < SIT; ++p) {
        int row = (tid >> 3) + p * 32;
        int c8 = (tid & 7) << 3;
        const float* g = Af + (size_t)(m0 + row) * K + (k0 + c8);
        float4 v0 = ((const float4*)g)[0];
        float4 v1 = ((const float4*)g)[1];
        u16x8 uv;
        uv[0] = f2bf(v0.x); uv[1] = f2bf(v0.y); uv[2] = f2bf(v0.z); uv[3] = f2bf(v0.w);
        uv[4] = f2bf(v1.x); uv[5] = f2bf(v1.y); uv[6] = f2bf(v1.z); uv[7] = f2bf(v1.w);
        *(u16x8*)&Asm[row * 64 + c8] = uv;
      }
    } else {
      const unsigned short* Ab = (const unsigned short*)Av;
      #pragma unroll
      for (int it = 0; it < SIT; ++it) {
        int li = it * 256 + tid;
        int row = li >> 3, c8 = (li & 7) << 3;
        const unsigned short* g = Ab + (size_t)(m0 + row) * K + (k0 + c8);
        gload_lds16(g, (char*)Asm + it * 4096 + w * 1024);
      }
    }
    __syncthreads();
    #pragma unroll
    for (int ks = 0; ks < 2; ++ks) {
      const int kb = ks * 32 + kg;
      bf16x8 af[FR], bfr[FR];
      #pragma unroll
      for (int i = 0; i < FR; ++i)
        af[i] = *(const bf16x8*)&Asm[(wr + i * 16 + lr) * 64 + kb];
      #pragma unroll
      for (int j = 0; j < FR; ++j)
        bfr[j] = *(const bf16x8*)&Bsm[(wc + j * 16 + lr) * 64 + kb];
      #pragma unroll
      for (int i = 0; i < FR; ++i)
        #pragma unroll
        for (int j = 0; j < FR; ++j)
          acc[i][j] = __builtin_amdgcn_mfma_f32_16x16x32_bf16(af[i], bfr[j], acc[i][j], 0, 0, 0);
    }
  }
  const int cr = (l >> 4) << 2;
  const int cc = l & 15;
  if (OUT_BIAS) {
    float* C = (float*)Cv;
    #pragma unroll
    for (int j = 0; j < FR; ++j) {
      int col = n0 + wc + j * 16 + cc;
      float bv = bias[col];
      #pragma unroll
      for (int i = 0; i < FR; ++i) {
        int rbase = m0 + wr + i * 16 + cr;
        #pragma unroll
        for (int r = 0; r < 4; ++r)
          C[(size_t)(rbase + r) * N + col] = acc[i][j][r] + bv;
      }
    }
  } else {
    unsigned short* C = (unsigned short*)Cv;
    #pragma unroll
    for (int j = 0; j < FR; ++j) {
      int col = n0 + wc + j * 16 + cc;
      #pragma unroll
      for (int i = 0; i < FR; ++i) {
        int rbase = m0 + wr + i * 16 + cr;
        #pragma unroll
        for (int r = 0; r < 4; ++r)
          C[(size_t)(rbase + r) * N + col] = f2bf(acc[i][j][r]);
      }
    }
  }
}

// ---------- 3b) 256x256 8-phase GEMM (final): C = A @ B^T + bias, fp32 out ----------
// 8 waves (wm=w>>2, wn=w&3). Per-wave C: quadrants (qi,qj): rows qi*128+wm*64+[0,64),
// cols qj*128+wn*32+[0,32). Phase p=(qi,qj) consumes exactly A-half qi, B-half qj.
// Stage order per tile: A0,B0,B1,A1 -> counted vmcnt(6) steady state, 4/2/0 drain.
// LDS 128 KiB: A dbuf 2x32KB then B dbuf 2x32KB. XOR swizzle byte^=(row&7)<<4.
template<int QI, int QJ>
__device__ __forceinline__ void phase_compute(const char* Ab, const char* Bb,
    int wm, int wn, int lr, int klo, int sw, f32x4 (&accq)[4][2])
{
  const char* Ah = Ab + QI * 16384;
  const char* Bh = Bb + QJ * 16384;
  #pragma unroll
  for (int ks = 0; ks < 2; ++ks) {
    const int cb = (ks * 64 + klo) ^ sw;
    bf16x8 av[4], bv[2];
    #pragma unroll
    for (int i = 0; i < 4; ++i) {
      const int ra = wm * 64 + i * 16 + lr;
      av[i] = *(const bf16x8*)(Ah + ra * 128 + cb);
    }
    #pragma unroll
    for (int j = 0; j < 2; ++j) {
      const int rb = wn * 32 + j * 16 + lr;
      bv[j] = *(const bf16x8*)(Bh + rb * 128 + cb);
    }
    __builtin_amdgcn_s_setprio(1);
    #pragma unroll
    for (int i = 0; i < 4; ++i)
      #pragma unroll
      for (int j = 0; j < 2; ++j)
        accq[i][j] = __builtin_amdgcn_mfma_f32_16x16x32_bf16(av[i], bv[j], accq[i][j], 0, 0, 0);
    __builtin_amdgcn_s_setprio(0);
  }
}

__global__ __launch_bounds__(512, 2)
void gemm256_kernel(const unsigned short* __restrict__ A,   // [M,K] bf16
                    const unsigned short* __restrict__ B,   // [N,K] bf16
                    float* __restrict__ C, const float* __restrict__ bias,
                    int N, int K)
{
  extern __shared__ __align__(16) char lds[];   // 131072 B
  const int tid = threadIdx.x;
  const int w = tid >> 6, l = tid & 63;
  const int wm = w >> 2, wn = w & 3;
  const int lr = l & 15;
  const int klo = (l >> 4) << 4;        // byte col of k-slot
  const int sw  = (lr & 7) << 4;        // read-side XOR swizzle

  const int nwg = gridDim.x;
  const int bid = blockIdx.x;
  const int cpx = nwg >> 3;
  const int swz = (bid & 7) * cpx + (bid >> 3);
  const int ntn = N >> 8;
  const int n0 = (swz % ntn) << 8;
  const int m0 = (swz / ntn) << 8;

  // staging source offsets (elements), inverse-swizzled global col
  unsigned int aoff[2][2], boff[2][2];
  #pragma unroll
  for (int q = 0; q < 2; ++q)
    #pragma unroll
    for (int it = 0; it < 2; ++it) {
      int L = it * 8192 + tid * 16;           // byte pos within half-tile
      int r = L >> 7;                          // row 0..127
      int cs = (L & 127) ^ ((r & 7) << 4);     // source col bytes (pre-swizzled)
      aoff[q][it] = (unsigned)(m0 + q * 128 + r) * K + (cs >> 1);
      boff[q][it] = (unsigned)(n0 + q * 128 + r) * K + (cs >> 1);
    }
  char* ldsA = lds;
  char* ldsB = lds + 65536;
  const int wdst = w * 1024;

#define STG_A(bufo, q, k0) do { \
    gload_lds16(A + aoff[q][0] + (k0), ldsA + (bufo) + (q) * 16384 + wdst); \
    gload_lds16(A + aoff[q][1] + (k0), ldsA + (bufo) + (q) * 16384 + 8192 + wdst); } while (0)
#define STG_B(bufo, q, k0) do { \
    gload_lds16(B + boff[q][0] + (k0), ldsB + (bufo) + (q) * 16384 + wdst); \
    gload_lds16(B + boff[q][1] + (k0), ldsB + (bufo) + (q) * 16384 + 8192 + wdst); } while (0)

  f32x4 acc[2][2][4][2] = {};

  // prologue: stage tile 0 into buf 0 (order A0,B0,B1,A1)
  STG_A(0, 0, 0); STG_B(0, 0, 0); STG_B(0, 1, 0); STG_A(0, 1, 0);

  const int NT = K >> 6;
  int curo = 0;
  for (int t = 0; t < NT - 1; ++t) {
    const int nxto = curo ^ 32768;
    const int k1 = (t + 1) << 6;
    // phase 0: quadrant (0,0); stage next A0; need cur A0,B0 (3 halves in flight)
    STG_A(nxto, 0, k1);
    asm volatile("s_waitcnt vmcnt(6)" ::: "memory");
    LBAR();
    phase_compute<0, 0>(ldsA + curo, ldsB + curo, wm, wn, lr, klo, sw, acc[0][0]);
    // phase 1: quadrant (0,1); stage next B0; need cur B1
    STG_B(nxto, 0, k1);
    asm volatile("s_waitcnt vmcnt(6)" ::: "memory");
    LBAR();
    phase_compute<0, 1>(ldsA + curo, ldsB + curo, wm, wn, lr, klo, sw, acc[0][1]);
    // phase 2: quadrant (1,0); stage next B1; need cur A1
    STG_B(nxto, 1, k1);
    asm volatile("s_waitcnt vmcnt(6)" ::: "memory");
    LBAR();
    phase_compute<1, 0>(ldsA + curo, ldsB + curo, wm, wn, lr, klo, sw, acc[1][0]);
    // phase 3: quadrant (1,1); stage next A1; nothing new needed
    STG_A(nxto, 1, k1);
    phase_compute<1, 1>(ldsA + curo, ldsB + curo, wm, wn, lr, klo, sw, acc[1][1]);
    curo = nxto;
  }
  // last tile: no staging, drain 4 -> 2 -> 0
  asm volatile("s_waitcnt vmcnt(4)" ::: "memory");
  LBAR();
  phase_compute<0, 0>(ldsA + curo, ldsB + curo, wm, wn, lr, klo, sw, acc[0][0]);
  asm volatile("s_waitcnt vmcnt(2)" ::: "memory");
  LBAR();
  phase_compute<0, 1>(ldsA + curo, ldsB + curo, wm, wn, lr, klo, sw, acc[0][1]);
  asm volatile("s_waitcnt vmcnt(0)" ::: "memory");
  LBAR();
  phase_compute<1, 0>(ldsA + curo, ldsB + curo, wm, wn, lr, klo, sw, acc[1][0]);
  phase_compute<1, 1>(ldsA + curo, ldsB + curo, wm, wn, lr, klo, sw, acc[1][1]);

  // epilogue: C/D layout col = lane&15, row = (lane>>4)*4 + reg
  const int cr = (l >> 4) << 2;
  const int cc = l & 15;
  #pragma unroll
  for (int qi = 0; qi < 2; ++qi)
    #pragma unroll
    for (int qj = 0; qj < 2; ++qj)
      #pragma unroll
      for (int j = 0; j < 2; ++j) {
        const int col = n0 + qj * 128 + wn * 32 + j * 16 + cc;
        const float bv = bias[col];
        #pragma unroll
        for (int i = 0; i < 4; ++i) {
          const int rbase = m0 + qi * 128 + wm * 64 + i * 16 + cr;
          #pragma unroll
          for (int r = 0; r < 4; ++r)
            C[(size_t)(rbase + r) * N + col] = acc[qi][qj][i][j][r] + bv;
        }
      }
#undef STG_A
#undef STG_B
}

// ---------- launch ----------
extern "C" void kernel_launch(void* const* d_in, const int* in_sizes, int n_in,
                              void* d_out, int out_size, void* d_ws, size_t ws_size,
                              hipStream_t stream) {
  (void)in_sizes; (void)n_in; (void)out_size;
  const float* x    = (const float*)d_in[0];
  const float* P0   = (const float*)d_in[1];
  const float* P1   = (const float*)d_in[2];
  const float* P2   = (const float*)d_in[3];
  const float* P3   = (const float*)d_in[4];
  const float* K0   = (const float*)d_in[5];
  const float* K1   = (const float*)d_in[6];
  const float* K2   = (const float*)d_in[7];
  const float* bias = (const float*)d_in[8];

  unsigned short* S  = (unsigned short*)d_ws;
  unsigned short* T0 = S + (size_t)4 * (1u << 20);
  unsigned short* T1 = T0 + (1u << 20);
  unsigned short* Xb = T1 + (1u << 20);
  const size_t need = ((size_t)6 * (1u << 20) + (size_t)32768 * 1024) * 2;
  const bool have_xb = ws_size >= need;

  softmax4_kernel<<<4096, 256, 0, stream>>>(P0, P1, P2, P3, S);
  if (have_xb)
    convert_x_kernel<<<2048, 256, 0, stream>>>(x, Xb, (32768 * 1024) / 8);

  const unsigned short* S0 = S;
  const unsigned short* S1 = S + (1u << 20);
  const unsigned short* S2 = S + (2u << 20);
  const unsigned short* S3 = S + (3u << 20);

  dim3 bdg(32, 4);
  blockdiagT_kernel<<<bdg, 256, 0, stream>>>(K0, S0, T0);
  gemm_bt_kernel<64, false, false><<<256, 256, 0, stream>>>((const void*)S1, T0,
                                                            (void*)T1, nullptr, 1024, 1024, 1024);
  blockdiagT_kernel<<<bdg, 256, 0, stream>>>(K1, T1, T0);
  gemm_bt_kernel<64, false, false><<<256, 256, 0, stream>>>((const void*)S2, T0,
                                                            (void*)T1, nullptr, 1024, 1024, 1024);
  blockdiagT_kernel<<<bdg, 256, 0, stream>>>(K2, T1, T0);
  gemm_bt_kernel<64, false, false><<<256, 256, 0, stream>>>((const void*)S3, T0,
                                                            (void*)T1, nullptr, 1024, 1024, 1024); // T1 = M [u][d]

  bool ok256 = false;
  if (have_xb) {
    hipError_t e = hipFuncSetAttribute((const void*)gemm256_kernel,
                                       hipFuncAttributeMaxDynamicSharedMemorySize, 131072);
    ok256 = (e == hipSuccess);
  }
  if (ok256) {
    gemm256_kernel<<<512, 512, 131072, stream>>>(Xb, T1, (float*)d_out, bias, 1024, 1024);
  } else if (have_xb) {
    gemm_bt_kernel<128, false, true><<<2048, 256, 0, stream>>>((const void*)Xb, T1,
                                                               d_out, bias, 32768, 1024, 1024);
  } else {
    gemm_bt_kernel<128, true, true><<<2048, 256, 0, stream>>>((const void*)x, T1,
                                                              d_out, bias, 32768, 1024, 1024);
  }
}